// Round 10
// baseline (657.665 us; speedup 1.0000x reference)
//
#include <hip/hip_runtime.h>

#define BB 8
#define CP 21
#define CF 22
#define CLOW 3
#define CHIGH 256
#define WW 80
#define VV 6400
#define EVERT 6320
#define EE 12640
#define TT 16
#define SIGMA_F 0.002f
#define ROOT 3240          // grid center (40,40)

#define NE (VV - 1)        // tree edges
#define NA (2 * NE)        // Euler arcs = 12798
#define NILA 0xFFFFu
#define CHUNK (VV / 256)   // 25
#define RMAX 13            // ceil_log2(VV) bound on doubling rounds
#define NGR (CF / 2)       // 11 channel pairs per tree

__device__ __forceinline__ void edge_uv(int e, int& u, int& v) {
  if (e < EVERT) { u = e; v = e + WW; }
  else { int e2 = e - EVERT; int r = e2 / (WW - 1); int c = e2 - r * (WW - 1); u = r * WW + c; v = u + 1; }
}

// ---------------- K1: softmax over 21 channels, per pixel ----------------
__global__ void k_softmax(const float* __restrict__ preds, float* __restrict__ prob) {
  int i = blockIdx.x * blockDim.x + threadIdx.x;
  if (i >= BB * VV) return;
  int b = i / VV, v = i - b * VV;
  const float* p = preds + (size_t)b * CP * VV + v;
  float m = -1e30f;
  #pragma unroll
  for (int c = 0; c < CP; c++) m = fmaxf(m, p[c * VV]);
  float e[CP], s = 0.f;
  #pragma unroll
  for (int c = 0; c < CP; c++) { float x = expf(p[c * VV] - m); e[c] = x; s += x; }
  float inv = 1.f / s;
  float* o = prob + (size_t)b * CP * VV + v;
  #pragma unroll
  for (int c = 0; c < CP; c++) o[c * VV] = e[c] * inv;
}

// ---------------- K2: edge keys (float64 cost, top-50-bits | edge idx) ----------------
__global__ void k_edgekey(const float* __restrict__ low, const float* __restrict__ high,
                          unsigned long long* __restrict__ ekey) {
  int i = blockIdx.x * blockDim.x + threadIdx.x;
  if (i >= TT * EE) return;
  int t = i / EE, e = i - t * EE;
  int u, v; edge_uv(e, u, v);
  double acc = 0.0;
  if (t < BB) {
    const float* emb = low + (size_t)t * CLOW * VV;
    for (int c = 0; c < CLOW; c++) { double d = (double)emb[c * VV + u] - (double)emb[c * VV + v]; acc += d * d; }
  } else {
    const float* emb = high + (size_t)(t - BB) * CHIGH * VV;
    for (int c = 0; c < CHIGH; c++) { double d = (double)emb[c * VV + u] - (double)emb[c * VV + v]; acc += d * d; }
  }
  unsigned long long bits = (unsigned long long)__double_as_longlong(acc);
  ekey[i] = (bits & ~0x3FFFULL) | (unsigned long long)e;
}

// ---------------- K3: parallel Boruvka MST with active-edge compaction ----------------
__global__ __launch_bounds__(1024) void k_boruvka(const unsigned long long* __restrict__ ekey,
    int* __restrict__ mstU, int* __restrict__ mstV) {
  int t = blockIdx.x;
  const unsigned long long* key = ekey + (size_t)t * EE;
  int* mu = mstU + t * VV;
  int* mv = mstV + t * VV;
  __shared__ int comp[VV];
  __shared__ unsigned long long bst[VV];
  __shared__ unsigned short tgtS[VV];
  __shared__ unsigned short el0[EE];
  __shared__ unsigned short el1[EE];
  __shared__ int changed, moved, cnt, necnt;
  int tid = threadIdx.x;
  const int nt = 1024;
  for (int v = tid; v < VV; v += nt) comp[v] = v;
  for (int e = tid; e < EE; e += nt) el0[e] = (unsigned short)e;
  if (tid == 0) cnt = 0;
  __syncthreads();
  unsigned short* els = el0;
  unsigned short* eld = el1;
  int ecnt = EE;
  for (int round = 0; round < 48 && ecnt > 0; round++) {
    for (int v = tid; v < VV; v += nt) bst[v] = ~0ULL;
    if (tid == 0) { changed = 0; necnt = 0; }
    __syncthreads();
    for (int j = tid; j < ecnt; j += nt) {
      int e = els[j];
      int u, v; edge_uv(e, u, v);
      int cu = comp[u], cv = comp[v];
      if (cu != cv) { unsigned long long k = key[e]; atomicMin(&bst[cu], k); atomicMin(&bst[cv], k); }
    }
    __syncthreads();
    for (int c = tid; c < VV; c += nt) {
      unsigned short tg = (unsigned short)NILA;
      if (comp[c] == c) {
        unsigned long long k = bst[c];
        if (k != ~0ULL) {
          int e = (int)(k & 0x3FFFULL);
          int u, v; edge_uv(e, u, v);
          int cu = comp[u], cv = comp[v];
          tg = (unsigned short)((cu == c) ? cv : cu);
        }
      }
      tgtS[c] = tg;
    }
    __syncthreads();
    for (int c = tid; c < VV; c += nt) {
      int o = tgtS[c];
      if (o == (int)NILA) continue;
      unsigned long long k = bst[c];
      if (bst[o] == k && c < o) continue;  // mutual minimum edge: smaller id stays root
      comp[c] = o;
      int slot = atomicAdd(&cnt, 1);
      int e = (int)(k & 0x3FFFULL);
      int u, v; edge_uv(e, u, v);
      mu[slot] = u; mv[slot] = v;
      changed = 1;
    }
    __syncthreads();
    if (!changed) break;
    for (int it = 0; it < 16; it++) {
      if (tid == 0) moved = 0;
      __syncthreads();
      for (int r = 0; r < 2; r++) {
        for (int v = tid; v < VV; v += nt) {
          int c = comp[v]; int cc = comp[c];
          if (cc != c) { comp[v] = cc; moved = 1; }
        }
        __syncthreads();
      }
      if (!moved) break;
    }
    for (int j = tid; j < ecnt; j += nt) {
      int e = els[j];
      int u, v; edge_uv(e, u, v);
      if (comp[u] != comp[v]) { int s = atomicAdd(&necnt, 1); eld[s] = (unsigned short)e; }
    }
    __syncthreads();
    ecnt = necnt;
    __syncthreads();
    unsigned short* tp = els; els = eld; eld = tp;
  }
}

// ---------------- K4: Euler-tour tree rooting at ROOT (position-space outputs) ----------------
__global__ __launch_bounds__(1024) void k_buildtree(const int* __restrict__ mstU, const int* __restrict__ mstV,
    int* __restrict__ ordG, int* __restrict__ spG, int* __restrict__ pvG,
    int* __restrict__ nlevG) {
  int t = blockIdx.x;
  const int* mu = mstU + t * VV;
  const int* mv = mstV + t * VV;
  int tid = threadIdx.x, nt = blockDim.x;

  __shared__ int buf4[32004];            // 128016-byte phase-overlapped arena
  char* buf = (char*)buf4;
  __shared__ int part[1024];
  __shared__ int lasts, smaxd;

  int* deg = (int*)(buf + 0);
  int* off = (int*)(buf + 25600);
  unsigned short* adjA = (unsigned short*)(buf + 51208);
  unsigned short* succ = (unsigned short*)(buf + 76808);
  unsigned short* r_a = (unsigned short*)(buf + 0);
  unsigned short* r_b = (unsigned short*)(buf + 25604);
  unsigned short* nx_b = (unsigned short*)(buf + 102408);
  short* tv = (short*)(buf + 51208);
  unsigned short* parentS = (unsigned short*)(buf + 76808);
  unsigned short* depthS  = (unsigned short*)(buf + 89608);
  int* lev = (int*)(buf + 0);
  int* cur = (int*)(buf + 25604);
  unsigned short* ordS = (unsigned short*)(buf + 102408);
  unsigned short* posS = (unsigned short*)(buf + 115208);

  // ---- Phase A: CSR + Euler successors ----
  for (int v = tid; v < VV; v += nt) deg[v] = 0;
  __syncthreads();
  for (int e = tid; e < NE; e += nt) { atomicAdd(&deg[mu[e]], 1); atomicAdd(&deg[mv[e]], 1); }
  __syncthreads();
  {
    const int SCH = 7;
    int base = tid * SCH;
    int s = 0;
    #pragma unroll
    for (int k = 0; k < SCH; k++) { int v = base + k; if (v < VV) s += deg[v]; }
    part[tid] = s;
    __syncthreads();
    for (int d = 1; d < 1024; d <<= 1) {
      int add = (tid >= d) ? part[tid - d] : 0;
      __syncthreads();
      part[tid] += add;
      __syncthreads();
    }
    int ex = part[tid] - s;
    #pragma unroll
    for (int k = 0; k < SCH; k++) { int v = base + k; if (v < VV) { off[v] = ex; ex += deg[v]; } }
    if (tid == 1023) off[VV] = ex;
  }
  __syncthreads();
  for (int v = tid; v < VV; v += nt) deg[v] = off[v];   // cursors
  __syncthreads();
  for (int e = tid; e < NE; e += nt) {
    int u = mu[e], v = mv[e];
    adjA[atomicAdd(&deg[u], 1)] = (unsigned short)(2 * e);
    adjA[atomicAdd(&deg[v], 1)] = (unsigned short)(2 * e + 1);
  }
  __syncthreads();
  for (int v = tid; v < VV; v += nt) {
    int b0 = off[v], dv = off[v + 1] - b0;
    for (int k = 0; k < dv; k++) {
      unsigned short a = adjA[b0 + k];
      unsigned short b = adjA[b0 + ((k + 1 == dv) ? 0 : k + 1)];
      succ[a ^ 1] = b;
    }
  }
  if (tid == 0) {
    lasts = adjA[off[ROOT] + (off[ROOT + 1] - off[ROOT]) - 1] ^ 1;
    smaxd = 0;
  }
  __syncthreads();
  if (tid == 0) succ[lasts] = (unsigned short)NILA;
  __syncthreads();
  // ---- Phase B: list ranking ----
  for (int a = tid; a < NA; a += nt) r_a[a] = (succ[a] == (unsigned short)NILA) ? 0 : 1;
  __syncthreads();
  {
    unsigned short *rx = r_a, *ry = r_b, *nxp = succ, *nyp = nx_b;
    for (int rd = 0; rd < 14; rd++) {
      for (int a = tid; a < NA; a += nt) {
        unsigned short n = nxp[a];
        if (n == (unsigned short)NILA) { ry[a] = rx[a]; nyp[a] = (unsigned short)NILA; }
        else { ry[a] = rx[a] + rx[n]; nyp[a] = nxp[n]; }
      }
      __syncthreads();
      unsigned short* tp;
      tp = rx; rx = ry; ry = tp;
      tp = nxp; nxp = nyp; nyp = tp;
    }
  }
  // ---- Phase C: tour values, depth scan, parent extraction ----
  for (int a = tid; a < NA; a += nt) {
    int p = (NA - 1) - (int)r_a[a];
    tv[p] = (r_a[a] > r_a[a ^ 1]) ? (short)1 : (short)-1;
  }
  __syncthreads();
  {
    const int SCH = 13;
    int base = tid * SCH;
    int lim = base + SCH; if (lim > NA) lim = NA;
    int s = 0;
    for (int j = base; j < lim; j++) s += tv[j];
    part[tid] = s;
    __syncthreads();
    for (int d = 1; d < 1024; d <<= 1) {
      int add = (tid >= d) ? part[tid - d] : 0;
      __syncthreads();
      part[tid] += add;
      __syncthreads();
    }
    int run = part[tid] - s;
    for (int j = base; j < lim; j++) { run += tv[j]; tv[j] = (short)run; }
  }
  __syncthreads();
  for (int a = tid; a < NA; a += nt) {
    if (r_a[a] > r_a[a ^ 1]) {   // down arc
      int e = a >> 1;
      int u = mu[e], v = mv[e];
      int head = (a & 1) ? u : v;
      int tail = (a & 1) ? v : u;
      int p = (NA - 1) - (int)r_a[a];
      int d = (int)tv[p];
      parentS[head] = (unsigned short)tail;
      depthS[head] = (unsigned short)d;
      atomicMax(&smaxd, d);
    }
  }
  if (tid == 0) { parentS[ROOT] = (unsigned short)ROOT; depthS[ROOT] = 0; }
  __syncthreads();
  int maxd = smaxd;
  // ---- Phase D: counting sort by depth ----
  for (int d = tid; d <= VV; d += nt) lev[d] = 0;
  __syncthreads();
  for (int v = tid; v < VV; v += nt) atomicAdd(&lev[depthS[v]], 1);
  __syncthreads();
  {
    const int SCH = 7;
    int base = tid * SCH;
    int s = 0;
    #pragma unroll
    for (int k = 0; k < SCH; k++) { int d = base + k; if (d <= VV) s += lev[d]; }
    part[tid] = s;
    __syncthreads();
    for (int d = 1; d < 1024; d <<= 1) {
      int add = (tid >= d) ? part[tid - d] : 0;
      __syncthreads();
      part[tid] += add;
      __syncthreads();
    }
    int ex = part[tid] - s;
    #pragma unroll
    for (int k = 0; k < SCH; k++) {
      int d = base + k;
      if (d <= VV) {
        int st = ex;
        ex += lev[d];
        if (d < VV) cur[d] = st;
      }
    }
  }
  __syncthreads();
  for (int v = tid; v < VV; v += nt) {
    int d = depthS[v];
    int slot = atomicAdd(&cur[d], 1);
    ordS[slot] = (unsigned short)v;
    posS[v] = (unsigned short)slot;
  }
  __syncthreads();
  for (int j = tid; j < VV; j += nt) {
    int v = ordS[j];
    int pv = parentS[v];
    ordG[t * VV + j] = v;
    pvG[t * VV + j] = pv;
    spG[t * VV + j] = posS[pv];
  }
  if (tid == 0) nlevG[t] = maxd + 1;
}

// ---------------- K5: per-position weight to parent (edge-key reuse; root -> 0) ----------------
__global__ void k_weights(const unsigned long long* __restrict__ ekey,
                          const int* __restrict__ ordG, const int* __restrict__ pvG,
                          float* __restrict__ wvp) {
  int i = blockIdx.x * blockDim.x + threadIdx.x;
  if (i >= TT * VV) return;
  int t = i / VV;
  int v = ordG[i], p = pvG[i];
  float wout;
  if (v == p) {
    wout = 0.0f;  // root: chain terminator (a=0)
  } else {
    int a = v < p ? v : p;
    int diff = v < p ? p - v : v - p;
    int e;
    if (diff == WW) e = a;
    else { int r = a / WW, c = a - r * WW; e = EVERT + r * (WW - 1) + c; }
    unsigned long long k = ekey[(size_t)t * EE + e];
    double cost = __longlong_as_double((long long)(k & ~0x3FFFULL));
    wout = expf(-(float)cost / SIGMA_F);
  }
  wvp[i] = wout;
}

// ---------------- K5b: precompute (a_r, p_r) doubling chain per tree ----------------
// apG[t][r][j] = (a, p-bits): 2^r-ancestor position and path product. Shared by both sweeps.
__global__ __launch_bounds__(256) void k_apchain(const float* __restrict__ wvp,
    const int* __restrict__ spG, const int* __restrict__ nlevG, float2* __restrict__ apG) {
  int t = blockIdx.x;
  __shared__ float2 ap0[VV];
  __shared__ float2 ap1[VV];
  int tid = threadIdx.x;
  int NL = nlevG[t];
  int R = 0; { int d = 1; while (d < NL) { d <<= 1; R++; } }
  float2* dst = apG + (size_t)t * RMAX * VV;
  #pragma unroll
  for (int k = 0; k < CHUNK; k++) {
    int j = tid + k * 256;
    float2 m = make_float2(wvp[t * VV + j], __int_as_float(spG[t * VV + j]));
    ap0[j] = m;
    dst[j] = m;
  }
  __syncthreads();
  float2 *s_ = ap0, *d_ = ap1;
  for (int r = 1; r < R; r++) {
    #pragma unroll
    for (int k = 0; k < CHUNK; k++) {
      int j = tid + k * 256;
      float2 m = s_[j];
      float2 o = m;
      if (m.x != 0.f) {
        float2 mp = s_[__float_as_int(m.y)];
        o.x = m.x * mp.x;
        o.y = mp.y;
      }
      d_[j] = o;
      dst[(size_t)r * VV + j] = o;
    }
    __syncthreads();
    float2* tp = s_; s_ = d_; d_ = tp;
  }
}

// ---------------- K6: tree filter — dual doubling sweeps, 2 channels per block ----------------
__global__ __launch_bounds__(256) void k_filter2(const float* __restrict__ Fsrc, float* __restrict__ Araw,
    const float2* __restrict__ apG, const int* __restrict__ ordG,
    const int* __restrict__ nlevG, int treeBase) {
  int blk = blockIdx.x;
  int b = blk / NGR, g = blk - b * NGR;
  int t = treeBase + b;
  int ch0 = 2 * g, ch1 = 2 * g + 1;     // ch1==CP for g==10 (ones channel)
  __shared__ float2 x0[VV];             // 51.2 KB
  __shared__ float2 x1[VV];             // 51.2 KB
  const float2* apT = apG + (size_t)t * RMAX * VV;
  const int* ord = ordG + t * VV;
  int tid = threadIdx.x;
  int NL = nlevG[t];
  int R = 0; { int d = 1; while (d < NL) { d <<= 1; R++; } }
  const bool norm_in = (treeBase != 0);
  // ---- load (gather via ord) ----
  #pragma unroll
  for (int k = 0; k < CHUNK; k++) {
    int j = tid + k * 256;
    int v = ord[j];
    float f0, f1;
    if (!norm_in) {
      f0 = Fsrc[((size_t)b * CP + ch0) * VV + v];
      f1 = (ch1 < CP) ? Fsrc[((size_t)b * CP + ch1) * VV + v] : 1.0f;
    } else {
      float inv = 1.0f / Fsrc[((size_t)b * CF + CP) * VV + v];
      f0 = Fsrc[((size_t)b * CF + ch0) * VV + v] * inv;
      f1 = (ch1 < CP) ? Fsrc[((size_t)b * CF + ch1) * VV + v] * inv : 1.0f;
    }
    x0[j] = make_float2(f0, f1);
  }
  __syncthreads();
  // ---- UP-sweep: S = prod_r (I + U^{2^r}) f via scatter-doubling ----
  float2 *xs = x0, *xd = x1;
  for (int r = 0; r < R; r++) {
    const float2* apr = apT + (size_t)r * VV;
    float2 xreg[CHUNK]; float areg[CHUNK]; int preg[CHUNK];
    #pragma unroll
    for (int k = 0; k < CHUNK; k++) {
      int j = tid + k * 256;
      float2 x = xs[j];
      xreg[k] = x;
      xd[j] = x;                        // copy base
      float2 m = apr[j];
      areg[k] = m.x;
      preg[k] = __float_as_int(m.y);
    }
    __syncthreads();                    // all copies done before scatters land
    #pragma unroll
    for (int k = 0; k < CHUNK; k++) {
      float a = areg[k];
      if (a != 0.f) {
        int p = preg[k];
        atomicAdd(&xd[p].x, a * xreg[k].x);
        atomicAdd(&xd[p].y, a * xreg[k].y);
      }
    }
    __syncthreads();
    float2* tp = xs; xs = xd; xd = tp;
  }
  // ---- affine init: b0 = S*(1-w^2); root has w=0 -> b0=S automatically ----
  #pragma unroll
  for (int k = 0; k < CHUNK; k++) {
    int j = tid + k * 256;
    float w = apT[j].x;
    float s = 1.f - w * w;
    float2 x = xs[j];
    xs[j] = make_float2(x.x * s, x.y * s);
  }
  __syncthreads();
  // ---- DOWN-sweep: gather-doubling (round-9 recurrence, shared chain) ----
  for (int r = 0; r < R; r++) {
    const float2* apr = apT + (size_t)r * VV;
    #pragma unroll
    for (int k = 0; k < CHUNK; k++) {
      int j = tid + k * 256;
      float2 m = apr[j];
      float2 x = xs[j];
      float a = m.x;
      if (a != 0.f) {
        float2 xp = xs[__float_as_int(m.y)];
        x.x = fmaf(a, xp.x, x.x);
        x.y = fmaf(a, xp.y, x.y);
      }
      xd[j] = x;
    }
    __syncthreads();
    float2* tp = xs; xs = xd; xd = tp;
  }
  // ---- store (scatter via ord) ----
  float* O0 = Araw + ((size_t)b * CF + ch0) * VV;
  float* O1 = Araw + ((size_t)b * CF + ch1) * VV;
  #pragma unroll
  for (int k = 0; k < CHUNK; k++) {
    int j = tid + k * 256;
    int v = ord[j];
    float2 x = xs[j];
    O0[v] = x.x;
    O1[v] = x.y;
  }
}

// ---------------- K7: ROI-masked L1 loss (fused normalize of stage 2) ----------------
__global__ void k_loss(const float* __restrict__ prob, const float* __restrict__ Araw2,
                       const int* __restrict__ roi, double* __restrict__ acc) {
  int i = blockIdx.x * blockDim.x + threadIdx.x;
  int tid = threadIdx.x;
  double s = 0.0, n = 0.0;
  if (i < BB * VV) {
    int b = i / VV, v = i - b * VV;
    if (roi[i] != 0) {
      n = 1.0;
      const float* pb = prob + (size_t)b * CP * VV + v;
      const float* ab = Araw2 + (size_t)b * CF * VV + v;
      float inv = 1.0f / ab[CP * VV];
      float ls = 0.f;
      #pragma unroll
      for (int c = 0; c < CP; c++) ls += fabsf(pb[c * VV] - ab[c * VV] * inv);
      s = (double)ls;
    }
  }
  __shared__ double rs[256], rn[256];
  rs[tid] = s; rn[tid] = n;
  __syncthreads();
  for (int d = 128; d > 0; d >>= 1) {
    if (tid < d) { rs[tid] += rs[tid + d]; rn[tid] += rn[tid + d]; }
    __syncthreads();
  }
  if (tid == 0) { atomicAdd(&acc[0], rs[0]); atomicAdd(&acc[1], rn[0]); }
}

__global__ void k_finalize(const double* __restrict__ acc, float* __restrict__ out) {
  out[0] = (acc[1] > 0.0) ? (float)(acc[0] / acc[1]) : 0.0f;
}

extern "C" void kernel_launch(void* const* d_in, const int* in_sizes, int n_in,
                              void* d_out, int out_size, void* d_ws, size_t ws_size,
                              hipStream_t stream) {
  const float* preds = (const float*)d_in[0];
  const float* low   = (const float*)d_in[1];
  const float* high  = (const float*)d_in[2];
  const int*   roi   = (const int*)d_in[3];
  float* out = (float*)d_out;

  char* w = (char*)d_ws;
  size_t off = 0;
  auto alloc = [&](size_t bytes) -> void* {
    void* p = w + off;
    off += (bytes + 255) & ~(size_t)255;
    return p;
  };
  float* prob  = (float*)alloc((size_t)BB * CP * VV * 4);
  float* Araw1 = (float*)alloc((size_t)BB * CF * VV * 4);
  float* Araw2 = (float*)alloc((size_t)BB * CF * VV * 4);
  unsigned long long* ekey = (unsigned long long*)alloc((size_t)TT * EE * 8);
  int* mstU = (int*)alloc((size_t)TT * VV * 4);
  int* mstV = (int*)alloc((size_t)TT * VV * 4);
  int* ordG = (int*)alloc((size_t)TT * VV * 4);
  int* spG  = (int*)alloc((size_t)TT * VV * 4);
  int* pvG  = (int*)alloc((size_t)TT * VV * 4);
  int* nlev = (int*)alloc((size_t)TT * 4);
  float* wvp = (float*)alloc((size_t)TT * VV * 4);
  float2* apG = (float2*)alloc((size_t)TT * RMAX * VV * 8);
  double* acc = (double*)alloc(16);

  hipMemsetAsync(acc, 0, 16, stream);

  k_softmax<<<(BB * VV + 255) / 256, 256, 0, stream>>>(preds, prob);
  k_edgekey<<<(TT * EE + 255) / 256, 256, 0, stream>>>(low, high, ekey);
  k_boruvka<<<TT, 1024, 0, stream>>>(ekey, mstU, mstV);
  k_buildtree<<<TT, 1024, 0, stream>>>(mstU, mstV, ordG, spG, pvG, nlev);
  k_weights<<<(TT * VV + 255) / 256, 256, 0, stream>>>(ekey, ordG, pvG, wvp);
  k_apchain<<<TT, 256, 0, stream>>>(wvp, spG, nlev, apG);
  k_filter2<<<BB * NGR, 256, 0, stream>>>(prob,  Araw1, apG, ordG, nlev, 0);
  k_filter2<<<BB * NGR, 256, 0, stream>>>(Araw1, Araw2, apG, ordG, nlev, BB);
  k_loss<<<(BB * VV + 255) / 256, 256, 0, stream>>>(prob, Araw2, roi, acc);
  k_finalize<<<1, 1, 0, stream>>>(acc, out);
}

// Round 11
// 464.635 us; speedup vs baseline: 1.4154x; 1.4154x over previous
//
#include <hip/hip_runtime.h>

#define BB 8
#define CP 21
#define CF 22
#define CLOW 3
#define CHIGH 256
#define WW 80
#define VV 6400
#define EVERT 6320
#define EE 12640
#define TT 16
#define SIGMA_F 0.002f
#define ROOT 3240          // grid center (40,40)

#define NE (VV - 1)        // tree edges
#define NA (2 * NE)        // Euler arcs = 12798
#define NILA 0xFFFFu
#define CHUNK (VV / 256)   // 25

__device__ __forceinline__ void edge_uv(int e, int& u, int& v) {
  if (e < EVERT) { u = e; v = e + WW; }
  else { int e2 = e - EVERT; int r = e2 / (WW - 1); int c = e2 - r * (WW - 1); u = r * WW + c; v = u + 1; }
}

// ---------------- K1: softmax over 21 channels, per pixel ----------------
__global__ void k_softmax(const float* __restrict__ preds, float* __restrict__ prob) {
  int i = blockIdx.x * blockDim.x + threadIdx.x;
  if (i >= BB * VV) return;
  int b = i / VV, v = i - b * VV;
  const float* p = preds + (size_t)b * CP * VV + v;
  float m = -1e30f;
  #pragma unroll
  for (int c = 0; c < CP; c++) m = fmaxf(m, p[c * VV]);
  float e[CP], s = 0.f;
  #pragma unroll
  for (int c = 0; c < CP; c++) { float x = expf(p[c * VV] - m); e[c] = x; s += x; }
  float inv = 1.f / s;
  float* o = prob + (size_t)b * CP * VV + v;
  #pragma unroll
  for (int c = 0; c < CP; c++) o[c * VV] = e[c] * inv;
}

// ---------------- K2: edge keys (float64 cost, top-50-bits | edge idx) ----------------
__global__ void k_edgekey(const float* __restrict__ low, const float* __restrict__ high,
                          unsigned long long* __restrict__ ekey) {
  int i = blockIdx.x * blockDim.x + threadIdx.x;
  if (i >= TT * EE) return;
  int t = i / EE, e = i - t * EE;
  int u, v; edge_uv(e, u, v);
  double acc = 0.0;
  if (t < BB) {
    const float* emb = low + (size_t)t * CLOW * VV;
    for (int c = 0; c < CLOW; c++) { double d = (double)emb[c * VV + u] - (double)emb[c * VV + v]; acc += d * d; }
  } else {
    const float* emb = high + (size_t)(t - BB) * CHIGH * VV;
    for (int c = 0; c < CHIGH; c++) { double d = (double)emb[c * VV + u] - (double)emb[c * VV + v]; acc += d * d; }
  }
  unsigned long long bits = (unsigned long long)__double_as_longlong(acc);
  ekey[i] = (bits & ~0x3FFFULL) | (unsigned long long)e;
}

// ---------------- K3: parallel Boruvka MST with active-edge compaction ----------------
__global__ __launch_bounds__(1024) void k_boruvka(const unsigned long long* __restrict__ ekey,
    int* __restrict__ mstU, int* __restrict__ mstV) {
  int t = blockIdx.x;
  const unsigned long long* key = ekey + (size_t)t * EE;
  int* mu = mstU + t * VV;
  int* mv = mstV + t * VV;
  __shared__ int comp[VV];
  __shared__ unsigned long long bst[VV];
  __shared__ unsigned short tgtS[VV];
  __shared__ unsigned short el0[EE];
  __shared__ unsigned short el1[EE];
  __shared__ int changed, moved, cnt, necnt;
  int tid = threadIdx.x;
  const int nt = 1024;
  for (int v = tid; v < VV; v += nt) comp[v] = v;
  for (int e = tid; e < EE; e += nt) el0[e] = (unsigned short)e;
  if (tid == 0) cnt = 0;
  __syncthreads();
  unsigned short* els = el0;
  unsigned short* eld = el1;
  int ecnt = EE;
  for (int round = 0; round < 48 && ecnt > 0; round++) {
    for (int v = tid; v < VV; v += nt) bst[v] = ~0ULL;
    if (tid == 0) { changed = 0; necnt = 0; }
    __syncthreads();
    for (int j = tid; j < ecnt; j += nt) {
      int e = els[j];
      int u, v; edge_uv(e, u, v);
      int cu = comp[u], cv = comp[v];
      if (cu != cv) { unsigned long long k = key[e]; atomicMin(&bst[cu], k); atomicMin(&bst[cv], k); }
    }
    __syncthreads();
    for (int c = tid; c < VV; c += nt) {
      unsigned short tg = (unsigned short)NILA;
      if (comp[c] == c) {
        unsigned long long k = bst[c];
        if (k != ~0ULL) {
          int e = (int)(k & 0x3FFFULL);
          int u, v; edge_uv(e, u, v);
          int cu = comp[u], cv = comp[v];
          tg = (unsigned short)((cu == c) ? cv : cu);
        }
      }
      tgtS[c] = tg;
    }
    __syncthreads();
    for (int c = tid; c < VV; c += nt) {
      int o = tgtS[c];
      if (o == (int)NILA) continue;
      unsigned long long k = bst[c];
      if (bst[o] == k && c < o) continue;  // mutual minimum edge: smaller id stays root
      comp[c] = o;
      int slot = atomicAdd(&cnt, 1);
      int e = (int)(k & 0x3FFFULL);
      int u, v; edge_uv(e, u, v);
      mu[slot] = u; mv[slot] = v;
      changed = 1;
    }
    __syncthreads();
    if (!changed) break;
    for (int it = 0; it < 16; it++) {
      if (tid == 0) moved = 0;
      __syncthreads();
      for (int r = 0; r < 2; r++) {
        for (int v = tid; v < VV; v += nt) {
          int c = comp[v]; int cc = comp[c];
          if (cc != c) { comp[v] = cc; moved = 1; }
        }
        __syncthreads();
      }
      if (!moved) break;
    }
    for (int j = tid; j < ecnt; j += nt) {
      int e = els[j];
      int u, v; edge_uv(e, u, v);
      if (comp[u] != comp[v]) { int s = atomicAdd(&necnt, 1); eld[s] = (unsigned short)e; }
    }
    __syncthreads();
    ecnt = necnt;
    __syncthreads();
    unsigned short* tp = els; els = eld; eld = tp;
  }
}

// ---------------- K4: Euler-tour tree rooting at ROOT (position-space outputs) ----------------
__global__ __launch_bounds__(1024) void k_buildtree(const int* __restrict__ mstU, const int* __restrict__ mstV,
    int* __restrict__ ordG, int* __restrict__ spG, int* __restrict__ pvG,
    int* __restrict__ lpG, int* __restrict__ nlevG) {
  int t = blockIdx.x;
  const int* mu = mstU + t * VV;
  const int* mv = mstV + t * VV;
  int tid = threadIdx.x, nt = blockDim.x;

  __shared__ int buf4[32004];            // 128016-byte phase-overlapped arena
  char* buf = (char*)buf4;
  __shared__ int part[1024];
  __shared__ int lasts, smaxd;

  int* deg = (int*)(buf + 0);
  int* off = (int*)(buf + 25600);
  unsigned short* adjA = (unsigned short*)(buf + 51208);
  unsigned short* succ = (unsigned short*)(buf + 76808);
  unsigned short* r_a = (unsigned short*)(buf + 0);
  unsigned short* r_b = (unsigned short*)(buf + 25604);
  unsigned short* nx_b = (unsigned short*)(buf + 102408);
  short* tv = (short*)(buf + 51208);
  unsigned short* parentS = (unsigned short*)(buf + 76808);
  unsigned short* depthS  = (unsigned short*)(buf + 89608);
  int* lev = (int*)(buf + 0);
  int* cur = (int*)(buf + 25604);
  unsigned short* ordS = (unsigned short*)(buf + 102408);
  unsigned short* posS = (unsigned short*)(buf + 115208);

  // ---- Phase A: CSR + Euler successors ----
  for (int v = tid; v < VV; v += nt) deg[v] = 0;
  __syncthreads();
  for (int e = tid; e < NE; e += nt) { atomicAdd(&deg[mu[e]], 1); atomicAdd(&deg[mv[e]], 1); }
  __syncthreads();
  {
    const int SCH = 7;
    int base = tid * SCH;
    int s = 0;
    #pragma unroll
    for (int k = 0; k < SCH; k++) { int v = base + k; if (v < VV) s += deg[v]; }
    part[tid] = s;
    __syncthreads();
    for (int d = 1; d < 1024; d <<= 1) {
      int add = (tid >= d) ? part[tid - d] : 0;
      __syncthreads();
      part[tid] += add;
      __syncthreads();
    }
    int ex = part[tid] - s;
    #pragma unroll
    for (int k = 0; k < SCH; k++) { int v = base + k; if (v < VV) { off[v] = ex; ex += deg[v]; } }
    if (tid == 1023) off[VV] = ex;
  }
  __syncthreads();
  for (int v = tid; v < VV; v += nt) deg[v] = off[v];   // cursors
  __syncthreads();
  for (int e = tid; e < NE; e += nt) {
    int u = mu[e], v = mv[e];
    adjA[atomicAdd(&deg[u], 1)] = (unsigned short)(2 * e);
    adjA[atomicAdd(&deg[v], 1)] = (unsigned short)(2 * e + 1);
  }
  __syncthreads();
  for (int v = tid; v < VV; v += nt) {
    int b0 = off[v], dv = off[v + 1] - b0;
    for (int k = 0; k < dv; k++) {
      unsigned short a = adjA[b0 + k];
      unsigned short b = adjA[b0 + ((k + 1 == dv) ? 0 : k + 1)];
      succ[a ^ 1] = b;
    }
  }
  if (tid == 0) {
    lasts = adjA[off[ROOT] + (off[ROOT + 1] - off[ROOT]) - 1] ^ 1;
    smaxd = 0;
  }
  __syncthreads();
  if (tid == 0) succ[lasts] = (unsigned short)NILA;
  __syncthreads();
  // ---- Phase B: list ranking ----
  for (int a = tid; a < NA; a += nt) r_a[a] = (succ[a] == (unsigned short)NILA) ? 0 : 1;
  __syncthreads();
  {
    unsigned short *rx = r_a, *ry = r_b, *nxp = succ, *nyp = nx_b;
    for (int rd = 0; rd < 14; rd++) {
      for (int a = tid; a < NA; a += nt) {
        unsigned short n = nxp[a];
        if (n == (unsigned short)NILA) { ry[a] = rx[a]; nyp[a] = (unsigned short)NILA; }
        else { ry[a] = rx[a] + rx[n]; nyp[a] = nxp[n]; }
      }
      __syncthreads();
      unsigned short* tp;
      tp = rx; rx = ry; ry = tp;
      tp = nxp; nxp = nyp; nyp = tp;
    }
  }
  // ---- Phase C: tour values, depth scan, parent extraction ----
  for (int a = tid; a < NA; a += nt) {
    int p = (NA - 1) - (int)r_a[a];
    tv[p] = (r_a[a] > r_a[a ^ 1]) ? (short)1 : (short)-1;
  }
  __syncthreads();
  {
    const int SCH = 13;
    int base = tid * SCH;
    int lim = base + SCH; if (lim > NA) lim = NA;
    int s = 0;
    for (int j = base; j < lim; j++) s += tv[j];
    part[tid] = s;
    __syncthreads();
    for (int d = 1; d < 1024; d <<= 1) {
      int add = (tid >= d) ? part[tid - d] : 0;
      __syncthreads();
      part[tid] += add;
      __syncthreads();
    }
    int run = part[tid] - s;
    for (int j = base; j < lim; j++) { run += tv[j]; tv[j] = (short)run; }
  }
  __syncthreads();
  for (int a = tid; a < NA; a += nt) {
    if (r_a[a] > r_a[a ^ 1]) {   // down arc
      int e = a >> 1;
      int u = mu[e], v = mv[e];
      int head = (a & 1) ? u : v;
      int tail = (a & 1) ? v : u;
      int p = (NA - 1) - (int)r_a[a];
      int d = (int)tv[p];
      parentS[head] = (unsigned short)tail;
      depthS[head] = (unsigned short)d;
      atomicMax(&smaxd, d);
    }
  }
  if (tid == 0) { parentS[ROOT] = (unsigned short)ROOT; depthS[ROOT] = 0; }
  __syncthreads();
  int maxd = smaxd;
  // ---- Phase D: counting sort by depth ----
  for (int d = tid; d <= VV; d += nt) lev[d] = 0;
  __syncthreads();
  for (int v = tid; v < VV; v += nt) atomicAdd(&lev[depthS[v]], 1);
  __syncthreads();
  {
    const int SCH = 7;
    int base = tid * SCH;
    int s = 0;
    #pragma unroll
    for (int k = 0; k < SCH; k++) { int d = base + k; if (d <= VV) s += lev[d]; }
    part[tid] = s;
    __syncthreads();
    for (int d = 1; d < 1024; d <<= 1) {
      int add = (tid >= d) ? part[tid - d] : 0;
      __syncthreads();
      part[tid] += add;
      __syncthreads();
    }
    int ex = part[tid] - s;
    #pragma unroll
    for (int k = 0; k < SCH; k++) {
      int d = base + k;
      if (d <= VV) {
        int st = ex;
        ex += lev[d];
        if (d < VV) cur[d] = st;
        lpG[t * (VV + 1) + d] = st;
      }
    }
  }
  __syncthreads();
  for (int v = tid; v < VV; v += nt) {
    int d = depthS[v];
    int slot = atomicAdd(&cur[d], 1);
    ordS[slot] = (unsigned short)v;
    posS[v] = (unsigned short)slot;
  }
  __syncthreads();
  for (int j = tid; j < VV; j += nt) {
    int v = ordS[j];
    int pv = parentS[v];
    ordG[t * VV + j] = v;
    pvG[t * VV + j] = pv;
    spG[t * VV + j] = posS[pv];
  }
  if (tid == 0) nlevG[t] = maxd + 1;
}

// ---------------- K5: per-position weight to parent (edge-key reuse; root -> 0) ----------------
__global__ void k_weights(const unsigned long long* __restrict__ ekey,
                          const int* __restrict__ ordG, const int* __restrict__ pvG,
                          float* __restrict__ wvp) {
  int i = blockIdx.x * blockDim.x + threadIdx.x;
  if (i >= TT * VV) return;
  int t = i / VV;
  int v = ordG[i], p = pvG[i];
  float wout;
  if (v == p) {
    wout = 0.0f;  // root: a=0 terminator, makes transform special-case-free
  } else {
    int a = v < p ? v : p;
    int diff = v < p ? p - v : v - p;
    int e;
    if (diff == WW) e = a;
    else { int r = a / WW, c = a - r * WW; e = EVERT + r * (WW - 1) + c; }
    unsigned long long k = ekey[(size_t)t * EE + e];
    double cost = __longlong_as_double((long long)(k & ~0x3FFFULL));
    wout = expf(-(float)cost / SIGMA_F);
  }
  wvp[i] = wout;
}

// ---------------- K6: tree filter — 2-level up-sweep chain + packed-float2 doubling down ----------------
__global__ __launch_bounds__(256) void k_filter_pc(const float* __restrict__ Fsrc, float* __restrict__ Araw,
    const float* __restrict__ wvp, const int* __restrict__ ordG, const int* __restrict__ spG,
    const int* __restrict__ lpG, const int* __restrict__ nlevG, int treeBase) {
  int blk = blockIdx.x;
  int b = blk / CF, ch = blk - b * CF;
  int t = treeBase + b;
  // Arena: ab0 [0,51200) {aliases sp2,cw2 during up-sweep} | ab1 [51200,102400) {aliases S,w}
  //        | sp0 | sp1 | lpS
  __shared__ alignas(16) char arena[140816];
  float2* ab0 = (float2*)(arena);
  unsigned short* sp2 = (unsigned short*)(arena);            // [0,12800)   up-sweep only
  float*  cw2 = (float*)(arena + 12800);                     // [12800,38400) up-sweep only
  float2* ab1 = (float2*)(arena + 51200);
  float*  S   = (float*)(arena + 51200);                     // dead after transform
  float*  w   = (float*)(arena + 76800);                     // dead after transform
  unsigned short* sp0 = (unsigned short*)(arena + 102400);
  unsigned short* sp1 = (unsigned short*)(arena + 115200);
  unsigned short* lpS = (unsigned short*)(arena + 128000);   // u16[VV+1]
  const int* ord = ordG + t * VV;
  const int* spt = spG + t * VV;
  const float* wsrc = wvp + t * VV;
  const int* lp = lpG + t * (VV + 1);
  int tid = threadIdx.x;
  int NL = nlevG[t];
  for (int j = tid; j <= NL; j += 256) lpS[j] = (unsigned short)lp[j];
  const bool norm_in = (treeBase != 0);
  for (int j = tid; j < VV; j += 256) {
    sp0[j] = (unsigned short)spt[j];
    w[j] = wsrc[j];
    float val;
    if (ch < CP) {
      int v = ord[j];
      if (!norm_in) val = Fsrc[((size_t)b * CP + ch) * VV + v];
      else          val = Fsrc[((size_t)b * CF + ch) * VV + v] / Fsrc[((size_t)b * CF + CP) * VV + v];
    } else val = 1.0f;
    S[j] = val;
  }
  __syncthreads();
  // grandparent pointers + 2-hop weights (root w=0 => level-1 cw2=0, harmless skip)
  for (int j = tid; j < VV; j += 256) {
    int p = sp0[j];
    sp2[j] = sp0[p];
    cw2[j] = w[j] * w[p];
  }
  __syncthreads();
  // ---- up-sweep: wave 0 only, TWO levels per dependent hop ----
  // Iteration (l, l-1): level-l lanes push cw2*S to grandparent (chain); level-(l-1)
  // lanes push w*f (pristine) to parent (chain); level-l's w*S push into l-1 is
  // DEFERRED one iteration (finalization only). All same-iteration writes target
  // levels disjoint from reads -> multi-pass safe.
  if (tid < 64) {
    int l = NL - 1;
    int prevA = -1;
    while (l >= 2) {
      int jlo = lpS[l - 1], jmid = lpS[l], jhi = lpS[l + 1];
      for (int j = jlo + tid; j < jhi; j += 64) {
        float s = S[j];
        if (j >= jmid) {
          float c2 = cw2[j];
          if (c2 != 0.f) atomicAdd(&S[sp2[j]], c2 * s);
        } else {
          atomicAdd(&S[sp0[j]], w[j] * s);
        }
      }
      if (prevA > 0) {
        int dlo = lpS[prevA], dhi = lpS[prevA + 1];
        for (int j = dlo + tid; j < dhi; j += 64) {
          atomicAdd(&S[sp0[j]], w[j] * S[j]);
        }
      }
      asm volatile("s_waitcnt lgkmcnt(0)" ::: "memory");
      __builtin_amdgcn_sched_barrier(0);
      prevA = l;
      l -= 2;
    }
    // epilogue: flush pending deferred push1
    if (prevA > 0) {
      int dlo = lpS[prevA], dhi = lpS[prevA + 1];
      for (int j = dlo + tid; j < dhi; j += 64) {
        atomicAdd(&S[sp0[j]], w[j] * S[j]);
      }
      asm volatile("s_waitcnt lgkmcnt(0)" ::: "memory");
      __builtin_amdgcn_sched_barrier(0);
    }
    if (l == 1) {  // level 1 was never a read level: its push1 completes the root
      int dlo = lpS[1], dhi = lpS[2];
      for (int j = dlo + tid; j < dhi; j += 64) {
        atomicAdd(&S[sp0[j]], w[j] * S[j]);
      }
      asm volatile("s_waitcnt lgkmcnt(0)" ::: "memory");
      __builtin_amdgcn_sched_barrier(0);
    }
  }
  __syncthreads();
  // ---- transform to packed affine: ab0[j] = (w, S*(1-w^2)); root w=0 -> (0, S) ----
  for (int j = tid; j < VV; j += 256) {
    float wv = w[j];
    ab0[j] = make_float2(wv, S[j] * (1.f - wv * wv));
  }
  __syncthreads();
  // ---- down-sweep: packed affine pointer doubling with converged-lane skip ----
  int rounds = 0;
  { int d = 1; while (d < NL) { d <<= 1; rounds++; } }
  float2 *abs_ = ab0, *abd_ = ab1;
  unsigned short *ps_ = sp0, *pd_ = sp1;
  for (int r = 0; r < rounds; r++) {
    #pragma unroll
    for (int k = 0; k < CHUNK; k++) {
      int j = tid + k * 256;
      float2 m = abs_[j];
      int p = ps_[j];
      float2 o = m;
      int pn = p;
      if (m.x != 0.f) {
        float2 mp = abs_[p];
        pn = ps_[p];
        o.x = m.x * mp.x;
        o.y = fmaf(m.x, mp.y, m.y);
      }
      abd_[j] = o;
      pd_[j] = (unsigned short)pn;
    }
    __syncthreads();
    float2* tf = abs_; abs_ = abd_; abd_ = tf;
    unsigned short* tu = ps_; ps_ = pd_; pd_ = tu;
  }
  // ---- scatter to vertex space ----
  float* Ob = Araw + ((size_t)b * CF + ch) * VV;
  for (int j = tid; j < VV; j += 256) Ob[ord[j]] = abs_[j].y;
}

// ---------------- K7: ROI-masked L1 loss (fused normalize of stage 2) ----------------
__global__ void k_loss(const float* __restrict__ prob, const float* __restrict__ Araw2,
                       const int* __restrict__ roi, double* __restrict__ acc) {
  int i = blockIdx.x * blockDim.x + threadIdx.x;
  int tid = threadIdx.x;
  double s = 0.0, n = 0.0;
  if (i < BB * VV) {
    int b = i / VV, v = i - b * VV;
    if (roi[i] != 0) {
      n = 1.0;
      const float* pb = prob + (size_t)b * CP * VV + v;
      const float* ab = Araw2 + (size_t)b * CF * VV + v;
      float inv = 1.0f / ab[CP * VV];
      float ls = 0.f;
      #pragma unroll
      for (int c = 0; c < CP; c++) ls += fabsf(pb[c * VV] - ab[c * VV] * inv);
      s = (double)ls;
    }
  }
  __shared__ double rs[256], rn[256];
  rs[tid] = s; rn[tid] = n;
  __syncthreads();
  for (int d = 128; d > 0; d >>= 1) {
    if (tid < d) { rs[tid] += rs[tid + d]; rn[tid] += rn[tid + d]; }
    __syncthreads();
  }
  if (tid == 0) { atomicAdd(&acc[0], rs[0]); atomicAdd(&acc[1], rn[0]); }
}

__global__ void k_finalize(const double* __restrict__ acc, float* __restrict__ out) {
  out[0] = (acc[1] > 0.0) ? (float)(acc[0] / acc[1]) : 0.0f;
}

extern "C" void kernel_launch(void* const* d_in, const int* in_sizes, int n_in,
                              void* d_out, int out_size, void* d_ws, size_t ws_size,
                              hipStream_t stream) {
  const float* preds = (const float*)d_in[0];
  const float* low   = (const float*)d_in[1];
  const float* high  = (const float*)d_in[2];
  const int*   roi   = (const int*)d_in[3];
  float* out = (float*)d_out;

  char* w = (char*)d_ws;
  size_t off = 0;
  auto alloc = [&](size_t bytes) -> void* {
    void* p = w + off;
    off += (bytes + 255) & ~(size_t)255;
    return p;
  };
  float* prob  = (float*)alloc((size_t)BB * CP * VV * 4);
  float* Araw1 = (float*)alloc((size_t)BB * CF * VV * 4);
  float* Araw2 = (float*)alloc((size_t)BB * CF * VV * 4);
  unsigned long long* ekey = (unsigned long long*)alloc((size_t)TT * EE * 8);
  int* mstU = (int*)alloc((size_t)TT * VV * 4);
  int* mstV = (int*)alloc((size_t)TT * VV * 4);
  int* ordG = (int*)alloc((size_t)TT * VV * 4);
  int* spG  = (int*)alloc((size_t)TT * VV * 4);
  int* pvG  = (int*)alloc((size_t)TT * VV * 4);
  int* lpG  = (int*)alloc((size_t)TT * (VV + 1) * 4);
  int* nlev = (int*)alloc((size_t)TT * 4);
  float* wvp = (float*)alloc((size_t)TT * VV * 4);
  double* acc = (double*)alloc(16);

  hipMemsetAsync(acc, 0, 16, stream);

  k_softmax<<<(BB * VV + 255) / 256, 256, 0, stream>>>(preds, prob);
  k_edgekey<<<(TT * EE + 255) / 256, 256, 0, stream>>>(low, high, ekey);
  k_boruvka<<<TT, 1024, 0, stream>>>(ekey, mstU, mstV);
  k_buildtree<<<TT, 1024, 0, stream>>>(mstU, mstV, ordG, spG, pvG, lpG, nlev);
  k_weights<<<(TT * VV + 255) / 256, 256, 0, stream>>>(ekey, ordG, pvG, wvp);
  k_filter_pc<<<BB * CF, 256, 0, stream>>>(prob,  Araw1, wvp, ordG, spG, lpG, nlev, 0);
  k_filter_pc<<<BB * CF, 256, 0, stream>>>(Araw1, Araw2, wvp, ordG, spG, lpG, nlev, BB);
  k_loss<<<(BB * VV + 255) / 256, 256, 0, stream>>>(prob, Araw2, roi, acc);
  k_finalize<<<1, 1, 0, stream>>>(acc, out);
}

// Round 12
// 340.933 us; speedup vs baseline: 1.9290x; 1.3628x over previous
//
#include <hip/hip_runtime.h>

#define BB 8
#define CP 21
#define CF 22
#define CLOW 3
#define CHIGH 256
#define WW 80
#define VV 6400
#define EVERT 6320
#define EE 12640
#define TT 16
#define SIGMA_F 0.002f
#define ROOT 3240          // grid center (40,40)

#define NE (VV - 1)        // tree edges
#define NA (2 * NE)        // Euler arcs = 12798
#define NILA 0xFFFFu

__device__ __forceinline__ void edge_uv(int e, int& u, int& v) {
  if (e < EVERT) { u = e; v = e + WW; }
  else { int e2 = e - EVERT; int r = e2 / (WW - 1); int c = e2 - r * (WW - 1); u = r * WW + c; v = u + 1; }
}

// ---------------- K1: softmax over 21 channels, per pixel ----------------
__global__ void k_softmax(const float* __restrict__ preds, float* __restrict__ prob) {
  int i = blockIdx.x * blockDim.x + threadIdx.x;
  if (i >= BB * VV) return;
  int b = i / VV, v = i - b * VV;
  const float* p = preds + (size_t)b * CP * VV + v;
  float m = -1e30f;
  #pragma unroll
  for (int c = 0; c < CP; c++) m = fmaxf(m, p[c * VV]);
  float e[CP], s = 0.f;
  #pragma unroll
  for (int c = 0; c < CP; c++) { float x = expf(p[c * VV] - m); e[c] = x; s += x; }
  float inv = 1.f / s;
  float* o = prob + (size_t)b * CP * VV + v;
  #pragma unroll
  for (int c = 0; c < CP; c++) o[c * VV] = e[c] * inv;
}

// ---------------- K2: edge keys (float64 cost, top-50-bits | edge idx) ----------------
__global__ void k_edgekey(const float* __restrict__ low, const float* __restrict__ high,
                          unsigned long long* __restrict__ ekey) {
  int i = blockIdx.x * blockDim.x + threadIdx.x;
  if (i >= TT * EE) return;
  int t = i / EE, e = i - t * EE;
  int u, v; edge_uv(e, u, v);
  double acc = 0.0;
  if (t < BB) {
    const float* emb = low + (size_t)t * CLOW * VV;
    for (int c = 0; c < CLOW; c++) { double d = (double)emb[c * VV + u] - (double)emb[c * VV + v]; acc += d * d; }
  } else {
    const float* emb = high + (size_t)(t - BB) * CHIGH * VV;
    for (int c = 0; c < CHIGH; c++) { double d = (double)emb[c * VV + u] - (double)emb[c * VV + v]; acc += d * d; }
  }
  unsigned long long bits = (unsigned long long)__double_as_longlong(acc);
  ekey[i] = (bits & ~0x3FFFULL) | (unsigned long long)e;
}

// ---------------- K3: parallel Boruvka MST, edge compaction + barrier-free compression ----------------
__global__ __launch_bounds__(1024) void k_boruvka(const unsigned long long* __restrict__ ekey,
    int* __restrict__ mstU, int* __restrict__ mstV) {
  int t = blockIdx.x;
  const unsigned long long* key = ekey + (size_t)t * EE;
  int* mu = mstU + t * VV;
  int* mv = mstV + t * VV;
  __shared__ int comp[VV];
  __shared__ unsigned long long bst[VV];
  __shared__ unsigned short tgtS[VV];
  __shared__ unsigned short el0[EE];
  __shared__ unsigned short el1[EE];
  __shared__ int changed, cnt, necnt;
  int tid = threadIdx.x;
  const int nt = 1024;
  for (int v = tid; v < VV; v += nt) comp[v] = v;
  for (int e = tid; e < EE; e += nt) el0[e] = (unsigned short)e;
  if (tid == 0) cnt = 0;
  __syncthreads();
  unsigned short* els = el0;
  unsigned short* eld = el1;
  int ecnt = EE;
  for (int round = 0; round < 48 && ecnt > 0; round++) {
    for (int v = tid; v < VV; v += nt) bst[v] = ~0ULL;
    if (tid == 0) { changed = 0; necnt = 0; }
    __syncthreads();
    // scan only still-crossing edges
    for (int j = tid; j < ecnt; j += nt) {
      int e = els[j];
      int u, v; edge_uv(e, u, v);
      int cu = comp[u], cv = comp[v];
      if (cu != cv) { unsigned long long k = key[e]; atomicMin(&bst[cu], k); atomicMin(&bst[cv], k); }
    }
    __syncthreads();
    // pass 1: hook targets
    for (int c = tid; c < VV; c += nt) {
      unsigned short tg = (unsigned short)NILA;
      if (comp[c] == c) {
        unsigned long long k = bst[c];
        if (k != ~0ULL) {
          int e = (int)(k & 0x3FFFULL);
          int u, v; edge_uv(e, u, v);
          int cu = comp[u], cv = comp[v];
          tg = (unsigned short)((cu == c) ? cv : cu);
        }
      }
      tgtS[c] = tg;
    }
    __syncthreads();
    // pass 2: hook
    for (int c = tid; c < VV; c += nt) {
      int o = tgtS[c];
      if (o == (int)NILA) continue;
      unsigned long long k = bst[c];
      if (bst[o] == k && c < o) continue;  // mutual minimum edge: smaller id stays root
      comp[c] = o;
      int slot = atomicAdd(&cnt, 1);
      int e = (int)(k & 0x3FFFULL);
      int u, v; edge_uv(e, u, v);
      mu[slot] = u; mv[slot] = v;
      changed = 1;
    }
    __syncthreads();
    if (!changed) break;
    // barrier-free full path compression: hook forest is acyclic, roots stable,
    // every intermediate value read lies on the path to the root.
    for (int v = tid; v < VV; v += nt) {
      int c = comp[v];
      int c2 = comp[c];
      if (c2 != c) {
        int r0 = c2;
        while (true) { int n = comp[r0]; if (n == r0) break; r0 = n; }
        comp[v] = r0;
      }
    }
    __syncthreads();
    // compact the active edge list under the compressed comp
    for (int j = tid; j < ecnt; j += nt) {
      int e = els[j];
      int u, v; edge_uv(e, u, v);
      if (comp[u] != comp[v]) { int s = atomicAdd(&necnt, 1); eld[s] = (unsigned short)e; }
    }
    __syncthreads();
    ecnt = necnt;
    __syncthreads();
    unsigned short* tp = els; els = eld; eld = tp;
  }
}

// ---------------- K4: Euler-tour tree rooting at ROOT (position-space outputs) ----------------
__global__ __launch_bounds__(1024) void k_buildtree(const int* __restrict__ mstU, const int* __restrict__ mstV,
    int* __restrict__ ordG, int* __restrict__ spG, int* __restrict__ pvG,
    int* __restrict__ lpG, int* __restrict__ nlevG) {
  int t = blockIdx.x;
  const int* mu = mstU + t * VV;
  const int* mv = mstV + t * VV;
  int tid = threadIdx.x, nt = blockDim.x;

  __shared__ int buf4[32004];            // 128016-byte phase-overlapped arena
  char* buf = (char*)buf4;
  __shared__ int part[1024];
  __shared__ int lasts, smaxd;

  int* deg = (int*)(buf + 0);
  int* off = (int*)(buf + 25600);
  unsigned short* adjA = (unsigned short*)(buf + 51208);
  unsigned short* succ = (unsigned short*)(buf + 76808);
  unsigned short* r_a = (unsigned short*)(buf + 0);
  unsigned short* r_b = (unsigned short*)(buf + 25604);
  unsigned short* nx_b = (unsigned short*)(buf + 102408);
  short* tv = (short*)(buf + 51208);
  unsigned short* parentS = (unsigned short*)(buf + 76808);
  unsigned short* depthS  = (unsigned short*)(buf + 89608);
  int* lev = (int*)(buf + 0);
  int* cur = (int*)(buf + 25604);
  unsigned short* ordS = (unsigned short*)(buf + 102408);
  unsigned short* posS = (unsigned short*)(buf + 115208);

  // ---- Phase A: CSR + Euler successors ----
  for (int v = tid; v < VV; v += nt) deg[v] = 0;
  __syncthreads();
  for (int e = tid; e < NE; e += nt) { atomicAdd(&deg[mu[e]], 1); atomicAdd(&deg[mv[e]], 1); }
  __syncthreads();
  {
    const int SCH = 7;
    int base = tid * SCH;
    int s = 0;
    #pragma unroll
    for (int k = 0; k < SCH; k++) { int v = base + k; if (v < VV) s += deg[v]; }
    part[tid] = s;
    __syncthreads();
    for (int d = 1; d < 1024; d <<= 1) {
      int add = (tid >= d) ? part[tid - d] : 0;
      __syncthreads();
      part[tid] += add;
      __syncthreads();
    }
    int ex = part[tid] - s;
    #pragma unroll
    for (int k = 0; k < SCH; k++) { int v = base + k; if (v < VV) { off[v] = ex; ex += deg[v]; } }
    if (tid == 1023) off[VV] = ex;
  }
  __syncthreads();
  for (int v = tid; v < VV; v += nt) deg[v] = off[v];   // cursors
  __syncthreads();
  for (int e = tid; e < NE; e += nt) {
    int u = mu[e], v = mv[e];
    adjA[atomicAdd(&deg[u], 1)] = (unsigned short)(2 * e);
    adjA[atomicAdd(&deg[v], 1)] = (unsigned short)(2 * e + 1);
  }
  __syncthreads();
  for (int v = tid; v < VV; v += nt) {
    int b0 = off[v], dv = off[v + 1] - b0;
    for (int k = 0; k < dv; k++) {
      unsigned short a = adjA[b0 + k];
      unsigned short b = adjA[b0 + ((k + 1 == dv) ? 0 : k + 1)];
      succ[a ^ 1] = b;
    }
  }
  if (tid == 0) {
    lasts = adjA[off[ROOT] + (off[ROOT + 1] - off[ROOT]) - 1] ^ 1;
    smaxd = 0;
  }
  __syncthreads();
  if (tid == 0) succ[lasts] = (unsigned short)NILA;
  __syncthreads();
  // ---- Phase B: list ranking ----
  for (int a = tid; a < NA; a += nt) r_a[a] = (succ[a] == (unsigned short)NILA) ? 0 : 1;
  __syncthreads();
  {
    unsigned short *rx = r_a, *ry = r_b, *nxp = succ, *nyp = nx_b;
    for (int rd = 0; rd < 14; rd++) {
      for (int a = tid; a < NA; a += nt) {
        unsigned short n = nxp[a];
        if (n == (unsigned short)NILA) { ry[a] = rx[a]; nyp[a] = (unsigned short)NILA; }
        else { ry[a] = rx[a] + rx[n]; nyp[a] = nxp[n]; }
      }
      __syncthreads();
      unsigned short* tp;
      tp = rx; rx = ry; ry = tp;
      tp = nxp; nxp = nyp; nyp = tp;
    }
  }
  // ---- Phase C: tour values, depth scan, parent extraction ----
  for (int a = tid; a < NA; a += nt) {
    int p = (NA - 1) - (int)r_a[a];
    tv[p] = (r_a[a] > r_a[a ^ 1]) ? (short)1 : (short)-1;
  }
  __syncthreads();
  {
    const int SCH = 13;
    int base = tid * SCH;
    int lim = base + SCH; if (lim > NA) lim = NA;
    int s = 0;
    for (int j = base; j < lim; j++) s += tv[j];
    part[tid] = s;
    __syncthreads();
    for (int d = 1; d < 1024; d <<= 1) {
      int add = (tid >= d) ? part[tid - d] : 0;
      __syncthreads();
      part[tid] += add;
      __syncthreads();
    }
    int run = part[tid] - s;
    for (int j = base; j < lim; j++) { run += tv[j]; tv[j] = (short)run; }
  }
  __syncthreads();
  for (int a = tid; a < NA; a += nt) {
    if (r_a[a] > r_a[a ^ 1]) {   // down arc
      int e = a >> 1;
      int u = mu[e], v = mv[e];
      int head = (a & 1) ? u : v;
      int tail = (a & 1) ? v : u;
      int p = (NA - 1) - (int)r_a[a];
      int d = (int)tv[p];
      parentS[head] = (unsigned short)tail;
      depthS[head] = (unsigned short)d;
      atomicMax(&smaxd, d);
    }
  }
  if (tid == 0) { parentS[ROOT] = (unsigned short)ROOT; depthS[ROOT] = 0; }
  __syncthreads();
  int maxd = smaxd;
  // ---- Phase D: counting sort by depth ----
  for (int d = tid; d <= VV; d += nt) lev[d] = 0;
  __syncthreads();
  for (int v = tid; v < VV; v += nt) atomicAdd(&lev[depthS[v]], 1);
  __syncthreads();
  {
    const int SCH = 7;
    int base = tid * SCH;
    int s = 0;
    #pragma unroll
    for (int k = 0; k < SCH; k++) { int d = base + k; if (d <= VV) s += lev[d]; }
    part[tid] = s;
    __syncthreads();
    for (int d = 1; d < 1024; d <<= 1) {
      int add = (tid >= d) ? part[tid - d] : 0;
      __syncthreads();
      part[tid] += add;
      __syncthreads();
    }
    int ex = part[tid] - s;
    #pragma unroll
    for (int k = 0; k < SCH; k++) {
      int d = base + k;
      if (d <= VV) {
        int st = ex;
        ex += lev[d];
        if (d < VV) cur[d] = st;
        lpG[t * (VV + 1) + d] = st;
      }
    }
  }
  __syncthreads();
  for (int v = tid; v < VV; v += nt) {
    int d = depthS[v];
    int slot = atomicAdd(&cur[d], 1);
    ordS[slot] = (unsigned short)v;
    posS[v] = (unsigned short)slot;
  }
  __syncthreads();
  for (int j = tid; j < VV; j += nt) {
    int v = ordS[j];
    int pv = parentS[v];
    ordG[t * VV + j] = v;
    pvG[t * VV + j] = pv;
    spG[t * VV + j] = posS[pv];
  }
  if (tid == 0) nlevG[t] = maxd + 1;
}

// ---------------- K5: per-position weight to parent (edge-key reuse; root -> 1, unused) ----------------
__global__ void k_weights(const unsigned long long* __restrict__ ekey,
                          const int* __restrict__ ordG, const int* __restrict__ pvG,
                          float* __restrict__ wvp) {
  int i = blockIdx.x * blockDim.x + threadIdx.x;
  if (i >= TT * VV) return;
  int t = i / VV;
  int v = ordG[i], p = pvG[i];
  float wout;
  if (v == p) {
    wout = 1.0f;  // root (overridden in filter transform)
  } else {
    int a = v < p ? v : p;
    int diff = v < p ? p - v : v - p;
    int e;
    if (diff == WW) e = a;
    else { int r = a / WW, c = a - r * WW; e = EVERT + r * (WW - 1) + c; }
    unsigned long long k = ekey[(size_t)t * EE + e];
    double cost = __longlong_as_double((long long)(k & ~0x3FFFULL));
    wout = expf(-(float)cost / SIGMA_F);
  }
  wvp[i] = wout;
}

// ---------------- K6: tree filter — level-sweep up (wave 0), packed-float2 doubling down ----------------
// 512 threads: bulk phases at 8 waves; up-sweep chain on wave 0 only.
__global__ __launch_bounds__(512) void k_filter_pc(const float* __restrict__ Fsrc, float* __restrict__ Araw,
    const float* __restrict__ wvp, const int* __restrict__ ordG, const int* __restrict__ spG,
    const int* __restrict__ lpG, const int* __restrict__ nlevG, int treeBase) {
  int blk = blockIdx.x;
  int b = blk / CF, ch = blk - b * CF;
  int t = treeBase + b;
  // LDS arena: ab0 [0,51200) | ab1 [51200,102400) {aliases S,w} | sp0 | sp1 | lpS
  __shared__ alignas(16) char arena[140816];
  float2* ab0 = (float2*)(arena);
  float2* ab1 = (float2*)(arena + 51200);
  float*  S   = (float*)(arena + 51200);     // dead after affine transform
  float*  w   = (float*)(arena + 76800);     // dead after affine transform
  unsigned short* sp0 = (unsigned short*)(arena + 102400);
  unsigned short* sp1 = (unsigned short*)(arena + 115200);
  unsigned short* lpS = (unsigned short*)(arena + 128000);  // u16[VV+1]
  const int* ord = ordG + t * VV;
  const int* spt = spG + t * VV;
  const float* wsrc = wvp + t * VV;
  const int* lp = lpG + t * (VV + 1);
  int tid = threadIdx.x;
  const int nt = 512;
  int NL = nlevG[t];
  for (int j = tid; j <= NL; j += nt) lpS[j] = (unsigned short)lp[j];
  const bool norm_in = (treeBase != 0);
  for (int j = tid; j < VV; j += nt) {
    sp0[j] = (unsigned short)spt[j];
    w[j] = wsrc[j];
    float val;
    if (ch < CP) {
      int v = ord[j];
      if (!norm_in) val = Fsrc[((size_t)b * CP + ch) * VV + v];
      else          val = Fsrc[((size_t)b * CF + ch) * VV + v] / Fsrc[((size_t)b * CF + CP) * VV + v];
    } else val = 1.0f;
    S[j] = val;
  }
  __syncthreads();
  // ---- up-sweep: wave 0 only, barrier-free, level bounds carried/prefetched ----
  if (tid < 64) {
    int s1 = lpS[NL];
    int s0 = lpS[NL - 1];
    for (int l = NL - 1; l >= 1; l--) {
      int s0n = (l > 1) ? (int)lpS[l - 1] : 0;
      for (int j = s0 + tid; j < s1; j += 64) {
        atomicAdd(&S[sp0[j]], w[j] * S[j]);
      }
      asm volatile("s_waitcnt lgkmcnt(0)" ::: "memory");
      __builtin_amdgcn_sched_barrier(0);
      s1 = s0; s0 = s0n;
    }
  }
  __syncthreads();
  // ---- transform to packed affine: ab0[j] = (a,b); root (pos 0) = (0, S[0]) ----
  for (int j = tid; j < VV; j += nt) {
    float wv = w[j];
    float a = (j == 0) ? 0.f : wv;
    float bv = (j == 0) ? S[0] : S[j] * (1.f - wv * wv);
    ab0[j] = make_float2(a, bv);
  }
  __syncthreads();
  // ---- down-sweep: packed affine pointer doubling with converged-lane skip ----
  int rounds = 0;
  { int d = 1; while (d < NL) { d <<= 1; rounds++; } }
  float2 *abs_ = ab0, *abd_ = ab1;          // round 0 writes over dead S,w
  unsigned short *ps_ = sp0, *pd_ = sp1;
  for (int r = 0; r < rounds; r++) {
    for (int j = tid; j < VV; j += nt) {
      float2 m = abs_[j];
      int p = ps_[j];
      float2 o = m;
      int pn = p;
      if (m.x != 0.f) {                      // not yet converged: compose with parent map
        float2 mp = abs_[p];
        pn = ps_[p];
        o.x = m.x * mp.x;
        o.y = fmaf(m.x, mp.y, m.y);
      }
      abd_[j] = o;
      pd_[j] = (unsigned short)pn;
    }
    __syncthreads();
    float2* tf = abs_; abs_ = abd_; abd_ = tf;
    unsigned short* tu = ps_; ps_ = pd_; pd_ = tu;
  }
  // ---- scatter to vertex space ----
  float* Ob = Araw + ((size_t)b * CF + ch) * VV;
  for (int j = tid; j < VV; j += nt) Ob[ord[j]] = abs_[j].y;
}

// ---------------- K7: ROI-masked L1 loss (fused normalize of stage 2) ----------------
__global__ void k_loss(const float* __restrict__ prob, const float* __restrict__ Araw2,
                       const int* __restrict__ roi, double* __restrict__ acc) {
  int i = blockIdx.x * blockDim.x + threadIdx.x;
  int tid = threadIdx.x;
  double s = 0.0, n = 0.0;
  if (i < BB * VV) {
    int b = i / VV, v = i - b * VV;
    if (roi[i] != 0) {
      n = 1.0;
      const float* pb = prob + (size_t)b * CP * VV + v;
      const float* ab = Araw2 + (size_t)b * CF * VV + v;
      float inv = 1.0f / ab[CP * VV];
      float ls = 0.f;
      #pragma unroll
      for (int c = 0; c < CP; c++) ls += fabsf(pb[c * VV] - ab[c * VV] * inv);
      s = (double)ls;
    }
  }
  __shared__ double rs[256], rn[256];
  rs[tid] = s; rn[tid] = n;
  __syncthreads();
  for (int d = 128; d > 0; d >>= 1) {
    if (tid < d) { rs[tid] += rs[tid + d]; rn[tid] += rn[tid + d]; }
    __syncthreads();
  }
  if (tid == 0) { atomicAdd(&acc[0], rs[0]); atomicAdd(&acc[1], rn[0]); }
}

__global__ void k_finalize(const double* __restrict__ acc, float* __restrict__ out) {
  out[0] = (acc[1] > 0.0) ? (float)(acc[0] / acc[1]) : 0.0f;
}

extern "C" void kernel_launch(void* const* d_in, const int* in_sizes, int n_in,
                              void* d_out, int out_size, void* d_ws, size_t ws_size,
                              hipStream_t stream) {
  const float* preds = (const float*)d_in[0];
  const float* low   = (const float*)d_in[1];
  const float* high  = (const float*)d_in[2];
  const int*   roi   = (const int*)d_in[3];
  float* out = (float*)d_out;

  char* w = (char*)d_ws;
  size_t off = 0;
  auto alloc = [&](size_t bytes) -> void* {
    void* p = w + off;
    off += (bytes + 255) & ~(size_t)255;
    return p;
  };
  float* prob  = (float*)alloc((size_t)BB * CP * VV * 4);
  float* Araw1 = (float*)alloc((size_t)BB * CF * VV * 4);
  float* Araw2 = (float*)alloc((size_t)BB * CF * VV * 4);
  unsigned long long* ekey = (unsigned long long*)alloc((size_t)TT * EE * 8);
  int* mstU = (int*)alloc((size_t)TT * VV * 4);
  int* mstV = (int*)alloc((size_t)TT * VV * 4);
  int* ordG = (int*)alloc((size_t)TT * VV * 4);
  int* spG  = (int*)alloc((size_t)TT * VV * 4);
  int* pvG  = (int*)alloc((size_t)TT * VV * 4);
  int* lpG  = (int*)alloc((size_t)TT * (VV + 1) * 4);
  int* nlev = (int*)alloc((size_t)TT * 4);
  float* wvp = (float*)alloc((size_t)TT * VV * 4);
  double* acc = (double*)alloc(16);

  hipMemsetAsync(acc, 0, 16, stream);

  k_softmax<<<(BB * VV + 255) / 256, 256, 0, stream>>>(preds, prob);
  k_edgekey<<<(TT * EE + 255) / 256, 256, 0, stream>>>(low, high, ekey);
  k_boruvka<<<TT, 1024, 0, stream>>>(ekey, mstU, mstV);
  k_buildtree<<<TT, 1024, 0, stream>>>(mstU, mstV, ordG, spG, pvG, lpG, nlev);
  k_weights<<<(TT * VV + 255) / 256, 256, 0, stream>>>(ekey, ordG, pvG, wvp);
  k_filter_pc<<<BB * CF, 512, 0, stream>>>(prob,  Araw1, wvp, ordG, spG, lpG, nlev, 0);
  k_filter_pc<<<BB * CF, 512, 0, stream>>>(Araw1, Araw2, wvp, ordG, spG, lpG, nlev, BB);
  k_loss<<<(BB * VV + 255) / 256, 256, 0, stream>>>(prob, Araw2, roi, acc);
  k_finalize<<<1, 1, 0, stream>>>(acc, out);
}